// Round 17
// baseline (183.537 us; speedup 1.0000x reference)
//
#include <hip/hip_runtime.h>
#include <hip/hip_bf16.h>

// Problem: B=16, S=1024, D=768, H=12, HD=64
// out = softmax((zWq^T)(zWk^T)^T / 8) (zWv^T) Wo^T + bo

typedef __attribute__((ext_vector_type(4))) float f32x4;
typedef __attribute__((ext_vector_type(16))) float f32x16;
typedef __attribute__((ext_vector_type(8))) __bf16 bf16x8;
typedef __attribute__((ext_vector_type(4))) unsigned int u32x4;

#if __has_builtin(__builtin_amdgcn_exp2f)
#define EXP2F __builtin_amdgcn_exp2f
#else
#define EXP2F exp2f
#endif

__device__ __forceinline__ unsigned short f2bf(float f) {
  union { float f; unsigned u; } v; v.f = f;
  unsigned r = v.u + 0x7FFFu + ((v.u >> 16) & 1u);  // RNE
  return (unsigned short)(r >> 16);
}

// v_cvt_pk_bf16_f32: dst.lo = bf16(a), dst.hi = bf16(b) — 1 VALU op
__device__ __forceinline__ unsigned cvtpk(float a, float b) {
  unsigned r;
  asm("v_cvt_pk_bf16_f32 %0, %1, %2" : "=v"(r) : "v"(a), "v"(b));
  return r;
}

// v_permlane32_swap_b32 a,b : a[32:63] <-> b[0:31]
// post: a' = {a.lo, b.lo}, b' = {a.hi, b.hi}.  MUST use two distinct values
// (self-swap destructively half-rotates — round-6 bug).
__device__ __forceinline__ void plswap(unsigned& a, unsigned& b) {
  asm("v_permlane32_swap_b32 %0, %1" : "+v"(a), "+v"(b));
}

__device__ __forceinline__ void gl_lds16(const void* g, void* l) {
  __builtin_amdgcn_global_load_lds(
      (const __attribute__((address_space(1))) void*)g,
      (__attribute__((address_space(3))) void*)l, 16, 0, 0);
}

// ---------------- f32 -> bf16 convert: z + 4 weights in ONE launch ----------------
__global__ void cvt_all(const float* __restrict__ z,
                        const float* __restrict__ i0, const float* __restrict__ i1,
                        const float* __restrict__ i2, const float* __restrict__ i3,
                        unsigned short* __restrict__ zo,
                        unsigned short* __restrict__ o0, unsigned short* __restrict__ o1,
                        unsigned short* __restrict__ o2, unsigned short* __restrict__ o3,
                        int nz4, int nw4) {
  const int bid = blockIdx.x;
  if (bid < 2048) {
    int i = bid * blockDim.x + threadIdx.x;
    const int stride = 2048 * blockDim.x;
    for (; i < nz4; i += stride) {
      float4 v = ((const float4*)z)[i];
      ushort4 o;
      o.x = f2bf(v.x); o.y = f2bf(v.y); o.z = f2bf(v.z); o.w = f2bf(v.w);
      ((ushort4*)zo)[i] = o;
    }
  } else {
    const int wb = bid - 2048;            // 0..575
    const int wsel = wb / 144;
    const int lb = wb % 144;
    const float* in = (wsel == 0) ? i0 : (wsel == 1) ? i1 : (wsel == 2) ? i2 : i3;
    unsigned short* out = (wsel == 0) ? o0 : (wsel == 1) ? o1 : (wsel == 2) ? o2 : o3;
    int i = lb * blockDim.x + threadIdx.x;
    const int stride = 144 * blockDim.x;
    for (; i < nw4; i += stride) {
      float4 v = ((const float4*)in)[i];
      ushort4 o;
      o.x = f2bf(v.x); o.y = f2bf(v.y); o.z = f2bf(v.z); o.w = f2bf(v.w);
      ((ushort4*)out)[i] = o;
    }
  }
}

// ---------------- fused QKV GEMM: C = A @ W^T (dbuf, XCD-chunked, swizzled, 32x32 MFMA) ----------------
// LDS [row][chunk] 8 chunks x 16B; stored chunk c holds global chunk c^(row&7).
// Wave tile 64x64 as 2x2 mfma_32x32x16 frags: 16 MFMA + 16 ds_read_b128 per K-step.
// C layout (verified in attn): col = lane&31 (B-operand row), reg r -> A-row (r&3)+8*(r>>2)+4*hi.
// which: 0->Q (scaled 0.125*log2e), 1->K, 2->V transposed [B*H][64][1024]
__global__ __launch_bounds__(256) void qkv_gemm(
    const unsigned short* __restrict__ A,
    const unsigned short* __restrict__ Wq,
    const unsigned short* __restrict__ Wk,
    const unsigned short* __restrict__ Wv,
    unsigned short* __restrict__ Qo,
    unsigned short* __restrict__ Ko,
    unsigned short* __restrict__ Vt) {
  __shared__ unsigned short As[2][128 * 64];
  __shared__ unsigned short Bs[2][128 * 64];
  const int bid = blockIdx.x;
  const int xcd = bid & 7, slot = bid >> 3;    // slot 0..287
  const int mt = xcd * 16 + slot / 18;
  const int rem = slot % 18;
  const int which = rem / 6;
  const int nt = rem % 6;
  const unsigned short* __restrict__ W =
      (which == 0) ? Wq : (which == 1) ? Wk : Wv;
  const int m0 = mt * 128;
  const int n0 = nt * 128;
  const int tid = threadIdx.x;
  const int lane = tid & 63;
  const int l31 = lane & 31;
  const int hi = lane >> 5;
  const int w = tid >> 6;
  const int wm = (w >> 1) * 64, wn = (w & 1) * 64;

  const int srow = tid >> 3;                   // base row (it=0); row = srow + it*32
  const int scg8 = (((tid & 7) ^ (srow & 7)) << 3);  // pre-swizzled source chunk (elems)

#define QSTAGE(bi, kt)                                                         \
  do {                                                                         \
    _Pragma("unroll") for (int it = 0; it < 4; ++it) {                         \
      int row = srow + it * 32;                                                \
      int dst = (row * 8 + (tid & 7)) * 8;                                     \
      gl_lds16(A + (size_t)(m0 + row) * 768 + (kt) + scg8, &As[bi][dst]);      \
      gl_lds16(W + (size_t)(n0 + row) * 768 + (kt) + scg8, &Bs[bi][dst]);      \
    }                                                                          \
  } while (0)

  f32x16 acc[2][2] = {};
  const int rx = l31 & 7;                      // fragment read-back XOR

  QSTAGE(0, 0);
  for (int kt = 0; kt < 768; kt += 64) {
    const int cur = (kt >> 6) & 1;
    if (kt < 704) {
      QSTAGE(cur ^ 1, kt + 64);
      asm volatile("s_waitcnt vmcnt(8)" ::: "memory");  // tile kt done, kt+64 in flight
    } else {
      asm volatile("s_waitcnt vmcnt(0)" ::: "memory");
    }
    __builtin_amdgcn_s_barrier();            // B1: tile kt visible to all waves
    __builtin_amdgcn_sched_barrier(0);
#pragma unroll
    for (int ks = 0; ks < 4; ++ks) {         // K-slices of 16
      bf16x8 a[2], b[2];
#pragma unroll
      for (int i = 0; i < 2; ++i)
        a[i] = *(const bf16x8*)&As[cur][(wm + i * 32 + l31) * 64 + (((ks * 2 + hi) ^ rx) << 3)];
#pragma unroll
      for (int j = 0; j < 2; ++j)
        b[j] = *(const bf16x8*)&Bs[cur][(wn + j * 32 + l31) * 64 + (((ks * 2 + hi) ^ rx) << 3)];
#pragma unroll
      for (int i = 0; i < 2; ++i)
#pragma unroll
        for (int j = 0; j < 2; ++j)
          acc[i][j] = __builtin_amdgcn_mfma_f32_32x32x16_bf16(
              a[i], b[j], acc[i][j], 0, 0, 0);
    }
    asm volatile("s_waitcnt lgkmcnt(0)" ::: "memory");
    __builtin_amdgcn_sched_barrier(0);
    __builtin_amdgcn_s_barrier();            // B2: all reads of buf cur done
  }

  if (which < 2) {
    unsigned short* __restrict__ O = which == 0 ? Qo : Ko;
    // Q pre-scaled so attention scores land in log2 domain: 1/8 * log2(e)
    const float scl = which == 0 ? 0.125f * 1.44269504088896f : 1.0f;
#pragma unroll
    for (int i = 0; i < 2; ++i)
#pragma unroll
      for (int j = 0; j < 2; ++j)
#pragma unroll
        for (int r = 0; r < 16; ++r) {
          int row = m0 + wm + i * 32 + (r & 3) + 8 * (r >> 2) + 4 * hi;
          int col = n0 + wn + j * 32 + l31;
          O[(size_t)row * 768 + col] = f2bf(acc[i][j][r] * scl);
        }
  } else {
    // V transposed: Vt[(b*12 + h)*64 + d][s]; regs r=4q+e are 4 consecutive rows
#pragma unroll
    for (int i = 0; i < 2; ++i)
#pragma unroll
      for (int j = 0; j < 2; ++j)
#pragma unroll
        for (int q = 0; q < 4; ++q) {
          int m = m0 + wm + i * 32 + 8 * q + 4 * hi;   // rows m..m+3
          int bb = m >> 10, s = m & 1023;
          int col = n0 + wn + j * 32 + l31;
          size_t off = ((size_t)(bb * 12 + (col >> 6)) * 64 + (col & 63)) * 1024 + s;
          ushort4 pk;
          pk.x = f2bf(acc[i][j][4 * q + 0]);
          pk.y = f2bf(acc[i][j][4 * q + 1]);
          pk.z = f2bf(acc[i][j][4 * q + 2]);
          pk.w = f2bf(acc[i][j][4 * q + 3]);
          *(ushort4*)(Vt + off) = pk;
        }
  }
#undef QSTAGE
}

// ---------------- flash attention (swapped QK^T, 64 q-rows/wave, no-max softmax) ----------------
// Q,K: [B,S,768] bf16 (Q pre-scaled, log2 domain); Vt: [B*12][64][1024] bf16
// grid 768, XCD-chunked. 4 waves/block, 64 q-rows/wave (2 groups of 32), KV tile 64.
// P-pack half-exchange via v_permlane32_swap (VALU) — distinct regs only (r6 lesson).
__global__ __launch_bounds__(256, 2) void attn_fwd(
    const unsigned short* __restrict__ Q,
    const unsigned short* __restrict__ K,
    const unsigned short* __restrict__ Vt,
    unsigned short* __restrict__ ctx) {
  __shared__ unsigned short Ks[2][64 * 64];
  __shared__ unsigned short Vs[2][64 * 64];
  const int wg = blockIdx.x;                // 0..767
  const int xcd = wg & 7, slot = wg >> 3;   // slot 0..95
  const int bh = xcd * 24 + (slot >> 2);    // 24 (b,h) per XCD
  const int qt = slot & 3;
  const int b = bh / 12, h = bh - b * 12;

  const int tid = threadIdx.x;
  const int lane = tid & 63;
  const int l31 = lane & 31;
  const int hi = lane >> 5;
  const int w = tid >> 6;
  const int qbase = qt * 256 + w * 64;

  const size_t qkoff = (size_t)b * (1024 * 768) + h * 64;
  const size_t vtoff = (size_t)bh * (64 * 1024);

  // ---- staging geometry: LDS [row][chunk^(row&7)] rows 0..63, 8 chunks x 16B ----
  const int sc = lane & 7;                  // LDS chunk this lane fills
  const int srsub = lane >> 3;              // row within 8-row segment
  const int scg = sc ^ srsub;               // global source chunk
  const int srow0 = w * 16 + srsub;         // j=0 row; j=1 row = +8

  const unsigned short* k0 = K + qkoff + scg * 8 + (size_t)srow0 * 768;
  const unsigned short* k1 = k0 + 8 * 768;
  const unsigned short* v0 = Vt + vtoff + scg * 8 + (size_t)srow0 * 1024;
  const unsigned short* v1 = v0 + 8 * 1024;
  const int d0 = srow0 * 64 + sc * 8;       // loop-invariant LDS dests
  const int d1 = d0 + 8 * 64;

#define STAGE(bi)                                                              \
  do {                                                                         \
    gl_lds16(k0, &Ks[bi][d0]);                                                 \
    gl_lds16(k1, &Ks[bi][d1]);                                                 \
    gl_lds16(v0, &Vs[bi][d0]);                                                 \
    gl_lds16(v1, &Vs[bi][d1]);                                                 \
    k0 += 64 * 768; k1 += 64 * 768; v0 += 64; v1 += 64;                        \
  } while (0)

  // ---- Q B-frags, 2 q-groups: rows qbase+l31 and qbase+32+l31 ----
  bf16x8 bqA[4], bqB[4];
  const unsigned short* Qp = Q + qkoff + (size_t)(qbase + l31) * 768 + hi * 8;
#pragma unroll
  for (int ks = 0; ks < 4; ++ks) {
    bqA[ks] = *(const bf16x8*)(Qp + ks * 16);
    bqB[ks] = *(const bf16x8*)(Qp + 32 * 768 + ks * 16);
  }

  f32x16 oA0 = {}, oA1 = {}, oB0 = {}, oB1 = {};  // lane = d (db*32+l31), q in regs
  float laccA[8] = {}, laccB[8] = {};             // exp-sum partials

  const int rxor = l31 & 7;        // frag read-back XOR

  STAGE(0);
  asm volatile("s_waitcnt vmcnt(0)");
  __syncthreads();

  for (int t = 0; t < 1024; t += 64) {
    const int cur = (t >> 6) & 1;
    if (t < 960) STAGE(cur ^ 1);

    // ---- K/V frags from LDS (shared across both q-groups) ----
    bf16x8 ak[2][4], bv[2][4];
#pragma unroll
    for (int kb2 = 0; kb2 < 2; ++kb2)
#pragma unroll
      for (int ks = 0; ks < 4; ++ks)
        ak[kb2][ks] = *(const bf16x8*)&Ks[cur][(kb2 * 32 + l31) * 64 + (((ks * 2 + hi) ^ rxor) * 8)];
#pragma unroll
    for (int db = 0; db < 2; ++db)
#pragma unroll
      for (int ks = 0; ks < 4; ++ks)
        bv[db][ks] = *(const bf16x8*)&Vs[cur][(db * 32 + l31) * 64 + (((ks * 2 + hi) ^ rxor) * 8)];

    // ---- S^T = K Q^T for both q-groups ----
    f32x16 sA0 = {}, sA1 = {}, sB0 = {}, sB1 = {};
    __builtin_amdgcn_s_setprio(1);
#pragma unroll
    for (int ks = 0; ks < 4; ++ks) {
      sA0 = __builtin_amdgcn_mfma_f32_32x32x16_bf16(ak[0][ks], bqA[ks], sA0, 0, 0, 0);
      sA1 = __builtin_amdgcn_mfma_f32_32x32x16_bf16(ak[1][ks], bqA[ks], sA1, 0, 0, 0);
    }
#pragma unroll
    for (int ks = 0; ks < 4; ++ks) {
      sB0 = __builtin_amdgcn_mfma_f32_32x32x16_bf16(ak[0][ks], bqB[ks], sB0, 0, 0, 0);
      sB1 = __builtin_amdgcn_mfma_f32_32x32x16_bf16(ak[1][ks], bqB[ks], sB1, 0, 0, 0);
    }
    __builtin_amdgcn_s_setprio(0);

    // ---- group A: exp2 (no max), partial sums, pack (permlane), PV ----
#pragma unroll
    for (int r = 0; r < 16; ++r) sA0[r] = EXP2F(sA0[r]);
#pragma unroll
    for (int r = 0; r < 16; ++r) sA1[r] = EXP2F(sA1[r]);
#pragma unroll
    for (int r = 0; r < 8; ++r)
      laccA[r] += (sA0[r] + sA0[r + 8]) + (sA1[r] + sA1[r + 8]);

    bf16x8 pa[4];
#pragma unroll
    for (int ks = 0; ks < 4; ++ks) {
      f32x16 ps = (ks < 2) ? sA0 : sA1;
      const int roff = (ks & 1) * 8;
      unsigned c01 = cvtpk(ps[roff + 0], ps[roff + 1]);
      unsigned c23 = cvtpk(ps[roff + 2], ps[roff + 3]);
      unsigned c45 = cvtpk(ps[roff + 4], ps[roff + 5]);
      unsigned c67 = cvtpk(ps[roff + 6], ps[roff + 7]);
      plswap(c01, c45);   // c01={c01.lo,c45.lo}, c45={c01.hi,c45.hi}
      plswap(c23, c67);
      u32x4 uw;
      uw[0] = c01; uw[1] = c23; uw[2] = c45; uw[3] = c67;
      pa[ks] = __builtin_bit_cast(bf16x8, uw);
    }
    __builtin_amdgcn_s_setprio(1);
#pragma unroll
    for (int ks = 0; ks < 4; ++ks) {
      oA0 = __builtin_amdgcn_mfma_f32_32x32x16_bf16(pa[ks], bv[0][ks], oA0, 0, 0, 0);
      oA1 = __builtin_amdgcn_mfma_f32_32x32x16_bf16(pa[ks], bv[1][ks], oA1, 0, 0, 0);
    }
    __builtin_amdgcn_s_setprio(0);

    // ---- group B: exp2, partial sums, pack (permlane), PV ----
#pragma unroll
    for (int r = 0; r < 16; ++r) sB0[r] = EXP2F(sB0[r]);
#pragma unroll
    for (int r = 0; r < 16; ++r) sB1[r] = EXP2F(sB1[r]);
#pragma unroll
    for (int r = 0; r < 8; ++r)
      laccB[r] += (sB0[r] + sB0[r + 8]) + (sB1[r] + sB1[r + 8]);

#pragma unroll
    for (int ks = 0; ks < 4; ++ks) {
      f32x16 ps = (ks < 2) ? sB0 : sB1;
      const int roff = (ks & 1) * 8;
      unsigned c01 = cvtpk(ps[roff + 0], ps[roff + 1]);
      unsigned c23 = cvtpk(ps[roff + 2], ps[roff + 3]);
      unsigned c45 = cvtpk(ps[roff + 4], ps[roff + 5]);
      unsigned c67 = cvtpk(ps[roff + 6], ps[roff + 7]);
      plswap(c01, c45);
      plswap(c23, c67);
      u32x4 uw;
      uw[0] = c01; uw[1] = c23; uw[2] = c45; uw[3] = c67;
      pa[ks] = __builtin_bit_cast(bf16x8, uw);
    }
    __builtin_amdgcn_s_setprio(1);
#pragma unroll
    for (int ks = 0; ks < 4; ++ks) {
      oB0 = __builtin_amdgcn_mfma_f32_32x32x16_bf16(pa[ks], bv[0][ks], oB0, 0, 0, 0);
      oB1 = __builtin_amdgcn_mfma_f32_32x32x16_bf16(pa[ks], bv[1][ks], oB1, 0, 0, 0);
    }
    __builtin_amdgcn_s_setprio(0);

    asm volatile("s_waitcnt vmcnt(0)");
    __syncthreads();
  }

  // ---- final l reduce + write (cross-half combine once, at the end; shfl is correct here) ----
  unsigned short* Cp = ctx + qkoff;
  {
    float lsA = ((laccA[0] + laccA[1]) + (laccA[2] + laccA[3])) +
                ((laccA[4] + laccA[5]) + (laccA[6] + laccA[7]));
    lsA += __shfl_xor(lsA, 32);
    float invA = 1.0f / lsA;
#pragma unroll
    for (int r = 0; r < 16; ++r) {
      int qof = (r & 3) + 8 * (r >> 2) + 4 * hi;
      float invO = __shfl(invA, qof);
      size_t rowo = (size_t)(qbase + qof) * 768 + l31;
      Cp[rowo] = f2bf(oA0[r] * invO);
      Cp[rowo + 32] = f2bf(oA1[r] * invO);
    }
  }
  {
    float lsB = ((laccB[0] + laccB[1]) + (laccB[2] + laccB[3])) +
                ((laccB[4] + laccB[5]) + (laccB[6] + laccB[7]));
    lsB += __shfl_xor(lsB, 32);
    float invB = 1.0f / lsB;
#pragma unroll
    for (int r = 0; r < 16; ++r) {
      int qof = (r & 3) + 8 * (r >> 2) + 4 * hi;
      float invO = __shfl(invB, qof);
      size_t rowo = (size_t)(qbase + 32 + qof) * 768 + l31;
      Cp[rowo] = f2bf(oB0[r] * invO);
      Cp[rowo + 32] = f2bf(oB1[r] * invO);
    }
  }
#undef STAGE
}

// ---------------- output projection: out = ctx @ Wo^T + bo (f32, dbuf, swizzled LDS) ----------------
__global__ __launch_bounds__(256) void oproj_gemm(
    const unsigned short* __restrict__ A,
    const unsigned short* __restrict__ W,
    const float* __restrict__ bias,
    float* __restrict__ out) {
  __shared__ unsigned short As[2][128 * 64];
  __shared__ unsigned short Bs[2][128 * 64];
  const int bid = blockIdx.x;               // 0..767
  const int xcd = bid & 7, slot = bid >> 3; // slot 0..95
  const int mt = xcd * 16 + slot / 6;
  const int nt = slot % 6;
  const int m0 = mt * 128;
  const int n0 = nt * 128;
  const int tid = threadIdx.x;
  const int lane = tid & 63;
  const int l15 = lane & 15, lg = lane >> 4;
  const int w = tid >> 6;
  const int wm = (w >> 1) * 64, wn = (w & 1) * 64;

  const int srow = tid >> 3;
  const int scg8 = (((tid & 7) ^ (srow & 7)) << 3);

#define OSTAGE(bi, kt)                                                         \
  do {                                                                         \
    _Pragma("unroll") for (int it = 0; it < 4; ++it) {                         \
      int row = srow + it * 32;                                                \
      int dst = (row * 8 + (tid & 7)) * 8;                                     \
      gl_lds16(A + (size_t)(m0 + row) * 768 + (kt) + scg8, &As[bi][dst]);      \
      gl_lds16(W + (size_t)(n0 + row) * 768 + (kt) + scg8, &Bs[bi][dst]);      \
    }                                                                          \
  } while (0)

  f32x4 acc[4][4] = {};
  const int rxf = l15 & 7;

  OSTAGE(0, 0);
  for (int kt = 0; kt < 768; kt += 64) {
    const int cur = (kt >> 6) & 1;
    if (kt < 704) {
      OSTAGE(cur ^ 1, kt + 64);
      asm volatile("s_waitcnt vmcnt(8)" ::: "memory");
    } else {
      asm volatile("s_waitcnt vmcnt(0)" ::: "memory");
    }
    __builtin_amdgcn_s_barrier();
    __builtin_amdgcn_sched_barrier(0);
#pragma unroll
    for (int kk = 0; kk < 64; kk += 32) {
      const int g0 = kk >> 3;
      bf16x8 a[4], b[4];
#pragma unroll
      for (int i = 0; i < 4; ++i)
        a[i] = *(const bf16x8*)&As[cur][(wm + i * 16 + l15) * 64 + (((g0 + lg) ^ rxf) << 3)];
#pragma unroll
      for (int j = 0; j < 4; ++j)
        b[j] = *(const bf16x8*)&Bs[cur][(wn + j * 16 + l15) * 64 + (((g0 + lg) ^ rxf) << 3)];
#pragma unroll
      for (int i = 0; i < 4; ++i)
#pragma unroll
        for (int j = 0; j < 4; ++j)
          acc[i][j] = __builtin_amdgcn_mfma_f32_16x16x32_bf16(
              a[i], b[j], acc[i][j], 0, 0, 0);
    }
    asm volatile("s_waitcnt lgkmcnt(0)" ::: "memory");
    __builtin_amdgcn_sched_barrier(0);
    __builtin_amdgcn_s_barrier();
  }

#pragma unroll
  for (int i = 0; i < 4; ++i)
#pragma unroll
    for (int j = 0; j < 4; ++j)
#pragma unroll
      for (int r = 0; r < 4; ++r) {
        int row = m0 + wm + i * 16 + lg * 4 + r;
        int col = n0 + wn + j * 16 + l15;
        out[(size_t)row * 768 + col] = acc[i][j][r] + bias[col];
      }
#undef OSTAGE
}

// ---------------- host launch ----------------
extern "C" void kernel_launch(void* const* d_in, const int* in_sizes, int n_in,
                              void* d_out, int out_size, void* d_ws, size_t ws_size,
                              hipStream_t stream) {
  const float* z = (const float*)d_in[0];
  const float* Wq = (const float*)d_in[1];
  const float* Wk = (const float*)d_in[2];
  const float* Wv = (const float*)d_in[3];
  const float* Wo = (const float*)d_in[4];
  const float* bo = (const float*)d_in[5];
  float* out = (float*)d_out;

  const size_t NZ = (size_t)16 * 1024 * 768;  // 12582912
  const size_t NW = (size_t)768 * 768;        // 589824

  unsigned short* zb = (unsigned short*)d_ws;
  unsigned short* Wqb = zb + NZ;
  unsigned short* Wkb = Wqb + NW;
  unsigned short* Wvb = Wkb + NW;
  unsigned short* Wob = Wvb + NW;
  unsigned short* Qb = Wob + NW;
  unsigned short* Kb = Qb + NZ;
  unsigned short* Vtb = Kb + NZ;
  unsigned short* Cb = Vtb + NZ;

  cvt_all<<<2624, 256, 0, stream>>>(z, Wq, Wk, Wv, Wo, zb, Wqb, Wkb, Wvb, Wob,
                                    (int)(NZ / 4), (int)(NW / 4));

  qkv_gemm<<<2304, 256, 0, stream>>>(zb, Wqb, Wkb, Wvb, Qb, Kb, Vtb);
  attn_fwd<<<768, 256, 0, stream>>>(Qb, Kb, Vtb, Cb);
  oproj_gemm<<<768, 256, 0, stream>>>(Cb, Wob, bo, out);
}

// Round 18
// 176.934 us; speedup vs baseline: 1.0373x; 1.0373x over previous
//
#include <hip/hip_runtime.h>
#include <hip/hip_bf16.h>

// Problem: B=16, S=1024, D=768, H=12, HD=64
// out = softmax((zWq^T)(zWk^T)^T / 8) (zWv^T) Wo^T + bo
// Banked configuration (round 16): total ~177 us.

typedef __attribute__((ext_vector_type(4))) float f32x4;
typedef __attribute__((ext_vector_type(16))) float f32x16;
typedef __attribute__((ext_vector_type(8))) __bf16 bf16x8;
typedef __attribute__((ext_vector_type(4))) unsigned int u32x4;

#if __has_builtin(__builtin_amdgcn_exp2f)
#define EXP2F __builtin_amdgcn_exp2f
#else
#define EXP2F exp2f
#endif

__device__ __forceinline__ unsigned short f2bf(float f) {
  union { float f; unsigned u; } v; v.f = f;
  unsigned r = v.u + 0x7FFFu + ((v.u >> 16) & 1u);  // RNE
  return (unsigned short)(r >> 16);
}

// v_cvt_pk_bf16_f32: dst.lo = bf16(a), dst.hi = bf16(b) — 1 VALU op
__device__ __forceinline__ unsigned cvtpk(float a, float b) {
  unsigned r;
  asm("v_cvt_pk_bf16_f32 %0, %1, %2" : "=v"(r) : "v"(a), "v"(b));
  return r;
}

// v_permlane32_swap_b32 a,b : a[32:63] <-> b[0:31]
// post: a' = {a.lo, b.lo}, b' = {a.hi, b.hi}.  MUST use two distinct values
// (self-swap destructively half-rotates — round-6 bug).
__device__ __forceinline__ void plswap(unsigned& a, unsigned& b) {
  asm("v_permlane32_swap_b32 %0, %1" : "+v"(a), "+v"(b));
}

__device__ __forceinline__ void gl_lds16(const void* g, void* l) {
  __builtin_amdgcn_global_load_lds(
      (const __attribute__((address_space(1))) void*)g,
      (__attribute__((address_space(3))) void*)l, 16, 0, 0);
}

// ---------------- f32 -> bf16 convert: z + 4 weights in ONE launch ----------------
__global__ void cvt_all(const float* __restrict__ z,
                        const float* __restrict__ i0, const float* __restrict__ i1,
                        const float* __restrict__ i2, const float* __restrict__ i3,
                        unsigned short* __restrict__ zo,
                        unsigned short* __restrict__ o0, unsigned short* __restrict__ o1,
                        unsigned short* __restrict__ o2, unsigned short* __restrict__ o3,
                        int nz4, int nw4) {
  const int bid = blockIdx.x;
  if (bid < 2048) {
    int i = bid * blockDim.x + threadIdx.x;
    const int stride = 2048 * blockDim.x;
    for (; i < nz4; i += stride) {
      float4 v = ((const float4*)z)[i];
      ushort4 o;
      o.x = f2bf(v.x); o.y = f2bf(v.y); o.z = f2bf(v.z); o.w = f2bf(v.w);
      ((ushort4*)zo)[i] = o;
    }
  } else {
    const int wb = bid - 2048;            // 0..575
    const int wsel = wb / 144;
    const int lb = wb % 144;
    const float* in = (wsel == 0) ? i0 : (wsel == 1) ? i1 : (wsel == 2) ? i2 : i3;
    unsigned short* out = (wsel == 0) ? o0 : (wsel == 1) ? o1 : (wsel == 2) ? o2 : o3;
    int i = lb * blockDim.x + threadIdx.x;
    const int stride = 144 * blockDim.x;
    for (; i < nw4; i += stride) {
      float4 v = ((const float4*)in)[i];
      ushort4 o;
      o.x = f2bf(v.x); o.y = f2bf(v.y); o.z = f2bf(v.z); o.w = f2bf(v.w);
      ((ushort4*)out)[i] = o;
    }
  }
}

// ---------------- fused QKV GEMM: C = A @ W^T (dbuf, XCD-chunked, XOR-swizzled LDS) ----------------
// LDS [row][chunk] 8 chunks x 16B; stored chunk c holds global chunk c^(row&7).
// which: 0->Q (scaled 0.125*log2e), 1->K, 2->V transposed [B*H][64][1024]
__global__ __launch_bounds__(256) void qkv_gemm(
    const unsigned short* __restrict__ A,
    const unsigned short* __restrict__ Wq,
    const unsigned short* __restrict__ Wk,
    const unsigned short* __restrict__ Wv,
    unsigned short* __restrict__ Qo,
    unsigned short* __restrict__ Ko,
    unsigned short* __restrict__ Vt) {
  __shared__ unsigned short As[2][128 * 64];
  __shared__ unsigned short Bs[2][128 * 64];
  const int bid = blockIdx.x;
  const int xcd = bid & 7, slot = bid >> 3;    // slot 0..287
  const int mt = xcd * 16 + slot / 18;
  const int rem = slot % 18;
  const int which = rem / 6;
  const int nt = rem % 6;
  const unsigned short* __restrict__ W =
      (which == 0) ? Wq : (which == 1) ? Wk : Wv;
  const int m0 = mt * 128;
  const int n0 = nt * 128;
  const int tid = threadIdx.x;
  const int lane = tid & 63;
  const int l15 = lane & 15, lg = lane >> 4;
  const int w = tid >> 6;
  const int wm = (w >> 1) * 64, wn = (w & 1) * 64;

  const int srow = tid >> 3;                   // base row (it=0); row = srow + it*32
  const int scg8 = (((tid & 7) ^ (srow & 7)) << 3);  // pre-swizzled source chunk (elems)

#define QSTAGE(bi, kt)                                                         \
  do {                                                                         \
    _Pragma("unroll") for (int it = 0; it < 4; ++it) {                         \
      int row = srow + it * 32;                                                \
      int dst = (row * 8 + (tid & 7)) * 8;                                     \
      gl_lds16(A + (size_t)(m0 + row) * 768 + (kt) + scg8, &As[bi][dst]);      \
      gl_lds16(W + (size_t)(n0 + row) * 768 + (kt) + scg8, &Bs[bi][dst]);      \
    }                                                                          \
  } while (0)

  f32x4 acc[4][4] = {};
  const int rxf = l15 & 7;                     // fragment read-back XOR

  QSTAGE(0, 0);
  for (int kt = 0; kt < 768; kt += 64) {
    const int cur = (kt >> 6) & 1;
    if (kt < 704) {
      QSTAGE(cur ^ 1, kt + 64);
      asm volatile("s_waitcnt vmcnt(8)" ::: "memory");  // tile kt done, kt+64 in flight
    } else {
      asm volatile("s_waitcnt vmcnt(0)" ::: "memory");
    }
    __builtin_amdgcn_s_barrier();            // B1: tile kt visible to all waves
    __builtin_amdgcn_sched_barrier(0);
#pragma unroll
    for (int kk = 0; kk < 64; kk += 32) {
      const int g0 = kk >> 3;                // global chunk base {0,4}
      bf16x8 a[4], b[4];
#pragma unroll
      for (int i = 0; i < 4; ++i)
        a[i] = *(const bf16x8*)&As[cur][(wm + i * 16 + l15) * 64 + (((g0 + lg) ^ rxf) << 3)];
#pragma unroll
      for (int j = 0; j < 4; ++j)
        b[j] = *(const bf16x8*)&Bs[cur][(wn + j * 16 + l15) * 64 + (((g0 + lg) ^ rxf) << 3)];
#pragma unroll
      for (int i = 0; i < 4; ++i)
#pragma unroll
        for (int j = 0; j < 4; ++j)
          acc[i][j] = __builtin_amdgcn_mfma_f32_16x16x32_bf16(
              a[i], b[j], acc[i][j], 0, 0, 0);
    }
    asm volatile("s_waitcnt lgkmcnt(0)" ::: "memory");
    __builtin_amdgcn_sched_barrier(0);
    __builtin_amdgcn_s_barrier();            // B2: all reads of buf cur done
  }

  if (which < 2) {
    unsigned short* __restrict__ O = which == 0 ? Qo : Ko;
    // Q pre-scaled so attention scores land in log2 domain: 1/8 * log2(e)
    const float scl = which == 0 ? 0.125f * 1.44269504088896f : 1.0f;
#pragma unroll
    for (int i = 0; i < 4; ++i)
#pragma unroll
      for (int j = 0; j < 4; ++j)
#pragma unroll
        for (int r = 0; r < 4; ++r) {
          int row = m0 + wm + i * 16 + lg * 4 + r;
          int col = n0 + wn + j * 16 + l15;
          O[(size_t)row * 768 + col] = f2bf(acc[i][j][r] * scl);
        }
  } else {
    // V transposed: Vt[(b*12 + h)*64 + d][s]
#pragma unroll
    for (int i = 0; i < 4; ++i)
#pragma unroll
      for (int j = 0; j < 4; ++j) {
        int m = m0 + wm + i * 16 + lg * 4;
        int bb = m >> 10, s = m & 1023;
        int col = n0 + wn + j * 16 + l15;
        size_t off = ((size_t)(bb * 12 + (col >> 6)) * 64 + (col & 63)) * 1024 + s;
        ushort4 pk;
        pk.x = f2bf(acc[i][j][0]);
        pk.y = f2bf(acc[i][j][1]);
        pk.z = f2bf(acc[i][j][2]);
        pk.w = f2bf(acc[i][j][3]);
        *(ushort4*)(Vt + off) = pk;
      }
  }
#undef QSTAGE
}

// ---------------- flash attention (swapped QK^T, 64 q-rows/wave, no-max softmax) ----------------
// Q,K: [B,S,768] bf16 (Q pre-scaled, log2 domain); Vt: [B*12][64][1024] bf16
// grid 768, XCD-chunked. 4 waves/block, 64 q-rows/wave (2 groups of 32), KV tile 64.
// P-pack half-exchange via v_permlane32_swap (VALU) — distinct regs only (r6 lesson).
__global__ __launch_bounds__(256, 2) void attn_fwd(
    const unsigned short* __restrict__ Q,
    const unsigned short* __restrict__ K,
    const unsigned short* __restrict__ Vt,
    unsigned short* __restrict__ ctx) {
  __shared__ unsigned short Ks[2][64 * 64];
  __shared__ unsigned short Vs[2][64 * 64];
  const int wg = blockIdx.x;                // 0..767
  const int xcd = wg & 7, slot = wg >> 3;   // slot 0..95
  const int bh = xcd * 24 + (slot >> 2);    // 24 (b,h) per XCD
  const int qt = slot & 3;
  const int b = bh / 12, h = bh - b * 12;

  const int tid = threadIdx.x;
  const int lane = tid & 63;
  const int l31 = lane & 31;
  const int hi = lane >> 5;
  const int w = tid >> 6;
  const int qbase = qt * 256 + w * 64;

  const size_t qkoff = (size_t)b * (1024 * 768) + h * 64;
  const size_t vtoff = (size_t)bh * (64 * 1024);

  // ---- staging geometry: LDS [row][chunk^(row&7)] rows 0..63, 8 chunks x 16B ----
  const int sc = lane & 7;                  // LDS chunk this lane fills
  const int srsub = lane >> 3;              // row within 8-row segment
  const int scg = sc ^ srsub;               // global source chunk
  const int srow0 = w * 16 + srsub;         // j=0 row; j=1 row = +8

  const unsigned short* k0 = K + qkoff + scg * 8 + (size_t)srow0 * 768;
  const unsigned short* k1 = k0 + 8 * 768;
  const unsigned short* v0 = Vt + vtoff + scg * 8 + (size_t)srow0 * 1024;
  const unsigned short* v1 = v0 + 8 * 1024;
  const int d0 = srow0 * 64 + sc * 8;       // loop-invariant LDS dests
  const int d1 = d0 + 8 * 64;

#define STAGE(bi)                                                              \
  do {                                                                         \
    gl_lds16(k0, &Ks[bi][d0]);                                                 \
    gl_lds16(k1, &Ks[bi][d1]);                                                 \
    gl_lds16(v0, &Vs[bi][d0]);                                                 \
    gl_lds16(v1, &Vs[bi][d1]);                                                 \
    k0 += 64 * 768; k1 += 64 * 768; v0 += 64; v1 += 64;                        \
  } while (0)

  // ---- Q B-frags, 2 q-groups: rows qbase+l31 and qbase+32+l31 ----
  bf16x8 bqA[4], bqB[4];
  const unsigned short* Qp = Q + qkoff + (size_t)(qbase + l31) * 768 + hi * 8;
#pragma unroll
  for (int ks = 0; ks < 4; ++ks) {
    bqA[ks] = *(const bf16x8*)(Qp + ks * 16);
    bqB[ks] = *(const bf16x8*)(Qp + 32 * 768 + ks * 16);
  }

  f32x16 oA0 = {}, oA1 = {}, oB0 = {}, oB1 = {};  // lane = d (db*32+l31), q in regs
  float laccA[8] = {}, laccB[8] = {};             // exp-sum partials

  const int rxor = l31 & 7;        // frag read-back XOR

  STAGE(0);
  asm volatile("s_waitcnt vmcnt(0)");
  __syncthreads();

  for (int t = 0; t < 1024; t += 64) {
    const int cur = (t >> 6) & 1;
    if (t < 960) STAGE(cur ^ 1);

    // ---- K/V frags from LDS (shared across both q-groups) ----
    bf16x8 ak[2][4], bv[2][4];
#pragma unroll
    for (int kb2 = 0; kb2 < 2; ++kb2)
#pragma unroll
      for (int ks = 0; ks < 4; ++ks)
        ak[kb2][ks] = *(const bf16x8*)&Ks[cur][(kb2 * 32 + l31) * 64 + (((ks * 2 + hi) ^ rxor) * 8)];
#pragma unroll
    for (int db = 0; db < 2; ++db)
#pragma unroll
      for (int ks = 0; ks < 4; ++ks)
        bv[db][ks] = *(const bf16x8*)&Vs[cur][(db * 32 + l31) * 64 + (((ks * 2 + hi) ^ rxor) * 8)];

    // ---- S^T = K Q^T for both q-groups ----
    f32x16 sA0 = {}, sA1 = {}, sB0 = {}, sB1 = {};
    __builtin_amdgcn_s_setprio(1);
#pragma unroll
    for (int ks = 0; ks < 4; ++ks) {
      sA0 = __builtin_amdgcn_mfma_f32_32x32x16_bf16(ak[0][ks], bqA[ks], sA0, 0, 0, 0);
      sA1 = __builtin_amdgcn_mfma_f32_32x32x16_bf16(ak[1][ks], bqA[ks], sA1, 0, 0, 0);
    }
#pragma unroll
    for (int ks = 0; ks < 4; ++ks) {
      sB0 = __builtin_amdgcn_mfma_f32_32x32x16_bf16(ak[0][ks], bqB[ks], sB0, 0, 0, 0);
      sB1 = __builtin_amdgcn_mfma_f32_32x32x16_bf16(ak[1][ks], bqB[ks], sB1, 0, 0, 0);
    }
    __builtin_amdgcn_s_setprio(0);

    // ---- group A: exp2 (no max), partial sums, pack (permlane), PV ----
#pragma unroll
    for (int r = 0; r < 16; ++r) sA0[r] = EXP2F(sA0[r]);
#pragma unroll
    for (int r = 0; r < 16; ++r) sA1[r] = EXP2F(sA1[r]);
#pragma unroll
    for (int r = 0; r < 8; ++r)
      laccA[r] += (sA0[r] + sA0[r + 8]) + (sA1[r] + sA1[r + 8]);

    bf16x8 pa[4];
#pragma unroll
    for (int ks = 0; ks < 4; ++ks) {
      f32x16 ps = (ks < 2) ? sA0 : sA1;
      const int roff = (ks & 1) * 8;
      unsigned c01 = cvtpk(ps[roff + 0], ps[roff + 1]);
      unsigned c23 = cvtpk(ps[roff + 2], ps[roff + 3]);
      unsigned c45 = cvtpk(ps[roff + 4], ps[roff + 5]);
      unsigned c67 = cvtpk(ps[roff + 6], ps[roff + 7]);
      plswap(c01, c45);   // c01={c01.lo,c45.lo}, c45={c01.hi,c45.hi}
      plswap(c23, c67);
      u32x4 uw;
      uw[0] = c01; uw[1] = c23; uw[2] = c45; uw[3] = c67;
      pa[ks] = __builtin_bit_cast(bf16x8, uw);
    }
    __builtin_amdgcn_s_setprio(1);
#pragma unroll
    for (int ks = 0; ks < 4; ++ks) {
      oA0 = __builtin_amdgcn_mfma_f32_32x32x16_bf16(pa[ks], bv[0][ks], oA0, 0, 0, 0);
      oA1 = __builtin_amdgcn_mfma_f32_32x32x16_bf16(pa[ks], bv[1][ks], oA1, 0, 0, 0);
    }
    __builtin_amdgcn_s_setprio(0);

    // ---- group B: exp2, partial sums, pack (permlane), PV ----
#pragma unroll
    for (int r = 0; r < 16; ++r) sB0[r] = EXP2F(sB0[r]);
#pragma unroll
    for (int r = 0; r < 16; ++r) sB1[r] = EXP2F(sB1[r]);
#pragma unroll
    for (int r = 0; r < 8; ++r)
      laccB[r] += (sB0[r] + sB0[r + 8]) + (sB1[r] + sB1[r + 8]);

#pragma unroll
    for (int ks = 0; ks < 4; ++ks) {
      f32x16 ps = (ks < 2) ? sB0 : sB1;
      const int roff = (ks & 1) * 8;
      unsigned c01 = cvtpk(ps[roff + 0], ps[roff + 1]);
      unsigned c23 = cvtpk(ps[roff + 2], ps[roff + 3]);
      unsigned c45 = cvtpk(ps[roff + 4], ps[roff + 5]);
      unsigned c67 = cvtpk(ps[roff + 6], ps[roff + 7]);
      plswap(c01, c45);
      plswap(c23, c67);
      u32x4 uw;
      uw[0] = c01; uw[1] = c23; uw[2] = c45; uw[3] = c67;
      pa[ks] = __builtin_bit_cast(bf16x8, uw);
    }
    __builtin_amdgcn_s_setprio(1);
#pragma unroll
    for (int ks = 0; ks < 4; ++ks) {
      oB0 = __builtin_amdgcn_mfma_f32_32x32x16_bf16(pa[ks], bv[0][ks], oB0, 0, 0, 0);
      oB1 = __builtin_amdgcn_mfma_f32_32x32x16_bf16(pa[ks], bv[1][ks], oB1, 0, 0, 0);
    }
    __builtin_amdgcn_s_setprio(0);

    asm volatile("s_waitcnt vmcnt(0)");
    __syncthreads();
  }

  // ---- final l reduce + write (cross-half combine once, at the end; shfl is correct here) ----
  unsigned short* Cp = ctx + qkoff;
  {
    float lsA = ((laccA[0] + laccA[1]) + (laccA[2] + laccA[3])) +
                ((laccA[4] + laccA[5]) + (laccA[6] + laccA[7]));
    lsA += __shfl_xor(lsA, 32);
    float invA = 1.0f / lsA;
#pragma unroll
    for (int r = 0; r < 16; ++r) {
      int qof = (r & 3) + 8 * (r >> 2) + 4 * hi;
      float invO = __shfl(invA, qof);
      size_t rowo = (size_t)(qbase + qof) * 768 + l31;
      Cp[rowo] = f2bf(oA0[r] * invO);
      Cp[rowo + 32] = f2bf(oA1[r] * invO);
    }
  }
  {
    float lsB = ((laccB[0] + laccB[1]) + (laccB[2] + laccB[3])) +
                ((laccB[4] + laccB[5]) + (laccB[6] + laccB[7]));
    lsB += __shfl_xor(lsB, 32);
    float invB = 1.0f / lsB;
#pragma unroll
    for (int r = 0; r < 16; ++r) {
      int qof = (r & 3) + 8 * (r >> 2) + 4 * hi;
      float invO = __shfl(invB, qof);
      size_t rowo = (size_t)(qbase + 32 + qof) * 768 + l31;
      Cp[rowo] = f2bf(oB0[r] * invO);
      Cp[rowo + 32] = f2bf(oB1[r] * invO);
    }
  }
#undef STAGE
}

// ---------------- output projection: out = ctx @ Wo^T + bo (f32, dbuf, swizzled LDS) ----------------
__global__ __launch_bounds__(256) void oproj_gemm(
    const unsigned short* __restrict__ A,
    const unsigned short* __restrict__ W,
    const float* __restrict__ bias,
    float* __restrict__ out) {
  __shared__ unsigned short As[2][128 * 64];
  __shared__ unsigned short Bs[2][128 * 64];
  const int bid = blockIdx.x;               // 0..767
  const int xcd = bid & 7, slot = bid >> 3; // slot 0..95
  const int mt = xcd * 16 + slot / 6;
  const int nt = slot % 6;
  const int m0 = mt * 128;
  const int n0 = nt * 128;
  const int tid = threadIdx.x;
  const int lane = tid & 63;
  const int l15 = lane & 15, lg = lane >> 4;
  const int w = tid >> 6;
  const int wm = (w >> 1) * 64, wn = (w & 1) * 64;

  const int srow = tid >> 3;
  const int scg8 = (((tid & 7) ^ (srow & 7)) << 3);

#define OSTAGE(bi, kt)                                                         \
  do {                                                                         \
    _Pragma("unroll") for (int it = 0; it < 4; ++it) {                         \
      int row = srow + it * 32;                                                \
      int dst = (row * 8 + (tid & 7)) * 8;                                     \
      gl_lds16(A + (size_t)(m0 + row) * 768 + (kt) + scg8, &As[bi][dst]);      \
      gl_lds16(W + (size_t)(n0 + row) * 768 + (kt) + scg8, &Bs[bi][dst]);      \
    }                                                                          \
  } while (0)

  f32x4 acc[4][4] = {};
  const int rxf = l15 & 7;

  OSTAGE(0, 0);
  for (int kt = 0; kt < 768; kt += 64) {
    const int cur = (kt >> 6) & 1;
    if (kt < 704) {
      OSTAGE(cur ^ 1, kt + 64);
      asm volatile("s_waitcnt vmcnt(8)" ::: "memory");
    } else {
      asm volatile("s_waitcnt vmcnt(0)" ::: "memory");
    }
    __builtin_amdgcn_s_barrier();
    __builtin_amdgcn_sched_barrier(0);
#pragma unroll
    for (int kk = 0; kk < 64; kk += 32) {
      const int g0 = kk >> 3;
      bf16x8 a[4], b[4];
#pragma unroll
      for (int i = 0; i < 4; ++i)
        a[i] = *(const bf16x8*)&As[cur][(wm + i * 16 + l15) * 64 + (((g0 + lg) ^ rxf) << 3)];
#pragma unroll
      for (int j = 0; j < 4; ++j)
        b[j] = *(const bf16x8*)&Bs[cur][(wn + j * 16 + l15) * 64 + (((g0 + lg) ^ rxf) << 3)];
#pragma unroll
      for (int i = 0; i < 4; ++i)
#pragma unroll
        for (int j = 0; j < 4; ++j)
          acc[i][j] = __builtin_amdgcn_mfma_f32_16x16x32_bf16(
              a[i], b[j], acc[i][j], 0, 0, 0);
    }
    asm volatile("s_waitcnt lgkmcnt(0)" ::: "memory");
    __builtin_amdgcn_sched_barrier(0);
    __builtin_amdgcn_s_barrier();
  }

#pragma unroll
  for (int i = 0; i < 4; ++i)
#pragma unroll
    for (int j = 0; j < 4; ++j)
#pragma unroll
      for (int r = 0; r < 4; ++r) {
        int row = m0 + wm + i * 16 + lg * 4 + r;
        int col = n0 + wn + j * 16 + l15;
        out[(size_t)row * 768 + col] = acc[i][j][r] + bias[col];
      }
#undef OSTAGE
}

// ---------------- host launch ----------------
extern "C" void kernel_launch(void* const* d_in, const int* in_sizes, int n_in,
                              void* d_out, int out_size, void* d_ws, size_t ws_size,
                              hipStream_t stream) {
  const float* z = (const float*)d_in[0];
  const float* Wq = (const float*)d_in[1];
  const float* Wk = (const float*)d_in[2];
  const float* Wv = (const float*)d_in[3];
  const float* Wo = (const float*)d_in[4];
  const float* bo = (const float*)d_in[5];
  float* out = (float*)d_out;

  const size_t NZ = (size_t)16 * 1024 * 768;  // 12582912
  const size_t NW = (size_t)768 * 768;        // 589824

  unsigned short* zb = (unsigned short*)d_ws;
  unsigned short* Wqb = zb + NZ;
  unsigned short* Wkb = Wqb + NW;
  unsigned short* Wvb = Wkb + NW;
  unsigned short* Wob = Wvb + NW;
  unsigned short* Qb = Wob + NW;
  unsigned short* Kb = Qb + NZ;
  unsigned short* Vtb = Kb + NZ;
  unsigned short* Cb = Vtb + NZ;

  cvt_all<<<2624, 256, 0, stream>>>(z, Wq, Wk, Wv, Wo, zb, Wqb, Wkb, Wvb, Wob,
                                    (int)(NZ / 4), (int)(NW / 4));

  qkv_gemm<<<2304, 256, 0, stream>>>(zb, Wqb, Wkb, Wvb, Qb, Kb, Vtb);
  attn_fwd<<<768, 256, 0, stream>>>(Qb, Kb, Vtb, Cb);
  oproj_gemm<<<768, 256, 0, stream>>>(Cb, Wob, bo, out);
}